// Round 5
// baseline (434.253 us; speedup 1.0000x reference)
//
#include <hip/hip_runtime.h>
#include <math.h>

#define NCAPS 2
#define NIN 91392      // 17*21*16*16
#define DIN 8
#define DOUT 16
#define BATCH 16
#define NCHUNK (NIN / 8)   // 11424 chunks of 8 n
#define MAXGRID 2856
#define TPB 256
#define PART_STRIDE 512    // 16 b * 2 j * 16 o per block

// Pass kernel: recompute u_hat[j,n,o] = sum_i x[b,n,i]*W[j,n,i,o] on the fly.
// PASS 0: s0 partial = sum_n u_hat (c=0.5 folded into reduce kernel)
// PASS 1: d = vin . u (diff over j) via 32-lane butterfly, c = sigmoid, s1 partial
// PASS 2: same with vin = v0+v1
template<int PASS>
__global__ __launch_bounds__(TPB) void caps_pass(
    const float* __restrict__ x, const float* __restrict__ W,
    const float* __restrict__ vin, float* __restrict__ part)
{
    const int t = threadIdx.x;
    const int o = t & 15;          // output dim
    const int j = (t >> 4) & 1;    // capsule
    const int g = t >> 5;          // n-subgroup 0..7
    const int bid = blockIdx.x;
    const int grid = gridDim.x;

    const float sgn = j ? -1.f : 1.f;

    // preload routing vector with sign folded in: vinreg[b] = sgn * vin[b][j][o]
    float vinreg[BATCH];
    if (PASS > 0) {
        #pragma unroll
        for (int b = 0; b < BATCH; ++b)
            vinreg[b] = sgn * vin[b * 32 + (t & 31)];
    }

    float acc[BATCH];
    #pragma unroll
    for (int b = 0; b < BATCH; ++b) acc[b] = 0.f;

    for (int chunk = bid; chunk < NCHUNK; chunk += grid) {
        const int n = chunk * 8 + g;

        // W[j][n][i][o], i stride = 16 floats (64B) -> 16-lane coalesced per i
        float Wr[DIN];
        const float* wp = W + ((size_t)(j * NIN + n) * DIN) * DOUT + o;
        #pragma unroll
        for (int i = 0; i < DIN; ++i) Wr[i] = wp[i * DOUT];

        const float* xp = x + (size_t)n * DIN;
        #pragma unroll
        for (int b = 0; b < BATCH; ++b) {
            const float* xb_p = xp + (size_t)b * (NIN * DIN);
            const float4 xa = *(const float4*)(xb_p);
            const float4 xb = *(const float4*)(xb_p + 4);
            float u = xa.x*Wr[0] + xa.y*Wr[1] + xa.z*Wr[2] + xa.w*Wr[3]
                    + xb.x*Wr[4] + xb.y*Wr[5] + xb.z*Wr[6] + xb.w*Wr[7];
            if (PASS == 0) {
                acc[b] += u;
            } else {
                // d = b0 - b1 = sum over 32 lanes of sgn * vin[j,o]*u[j,o]
                float m = vinreg[b] * u;
                m += __shfl_xor(m, 1);
                m += __shfl_xor(m, 2);
                m += __shfl_xor(m, 4);
                m += __shfl_xor(m, 8);
                m += __shfl_xor(m, 16);
                // softmax over 2 caps: c_j = sigmoid(sgn_j * d)
                const float c = __builtin_amdgcn_rcpf(1.f + __expf(-sgn * m));
                acc[b] += c * u;
            }
        }
    }

    // reduce over the 8 n-subgroups: pair within wave, then across 4 waves
    #pragma unroll
    for (int b = 0; b < BATCH; ++b) acc[b] += __shfl_xor(acc[b], 32);

    __shared__ float red[4][32][BATCH];
    const int wave = t >> 6;
    const int lane = t & 63;
    if (lane < 32) {
        #pragma unroll
        for (int b = 0; b < BATCH; ++b) red[wave][lane][b] = acc[b];
    }
    __syncthreads();
    if (t < 32) {
        #pragma unroll
        for (int b = 0; b < BATCH; ++b) {
            float s = red[0][t][b] + red[1][t][b] + red[2][t][b] + red[3][t][b];
            part[(size_t)bid * PART_STRIDE + b * 32 + t] = s;  // [bid][b][j*16+o]
        }
    }
}

// Reduce partials -> s[b,j,o], squash -> v. 32 blocks = one per (b,j).
// PASS 0: scale s by 0.5 (uniform softmax); writes v0
// PASS 1: writes v0+v1 (routing logits are linear in accumulated v)
// PASS 2: writes final v to d_out
template<int PASS>
__global__ __launch_bounds__(256) void caps_reduce(
    const float* __restrict__ part, const float* __restrict__ vprev,
    float* __restrict__ vout, int gridA)
{
    const int blk = blockIdx.x;   // b*2 + j
    const int b = blk >> 1, j = blk & 1;
    const int t = threadIdx.x;
    const int o = t & 15;
    const int ch = t >> 4;        // 16 chunks over gridA rows
    float s = 0.f;
    for (int g = ch; g < gridA; g += 16)
        s += part[(size_t)g * PART_STRIDE + b * 32 + j * 16 + o];
    __shared__ float red[256];
    red[t] = s;
    __syncthreads();
    if (t < 16) {
        float sv = 0.f;
        #pragma unroll
        for (int c = 0; c < 16; ++c) sv += red[c * 16 + t];
        if (PASS == 0) sv *= 0.5f;
        // squash: v = s * sn/(1+sn)/sqrt(sn+eps), sn = |s|^2 over o (16 lanes)
        float sq = sv * sv;
        sq += __shfl_xor(sq, 1);
        sq += __shfl_xor(sq, 2);
        sq += __shfl_xor(sq, 4);
        sq += __shfl_xor(sq, 8);
        const float sn = sq;
        float v = sv * sn / ((1.f + sn) * sqrtf(sn + 1e-7f));
        if (PASS == 1) v += vprev[b * 32 + j * 16 + o];
        vout[b * 32 + j * 16 + o] = v;
    }
}

extern "C" void kernel_launch(void* const* d_in, const int* in_sizes, int n_in,
                              void* d_out, int out_size, void* d_ws, size_t ws_size,
                              hipStream_t stream) {
    const float* x = (const float*)d_in[0];
    const float* W = (const float*)d_in[1];
    float* out = (float*)d_out;

    // grid sized for occupancy, clamped to available workspace (deterministic)
    size_t maxg = (ws_size - 4096) / (PART_STRIDE * sizeof(float));
    int GRID = (int)(maxg < MAXGRID ? maxg : MAXGRID);
    if (GRID < 1) GRID = 1;

    float* part = (float*)d_ws;                                // GRID*512 floats
    float* v0   = part + (size_t)GRID * PART_STRIDE;           // 512
    float* vsum = v0 + 512;                                    // 512

    caps_pass<0><<<GRID, TPB, 0, stream>>>(x, W, nullptr, part);
    caps_reduce<0><<<32, 256, 0, stream>>>(part, nullptr, v0, GRID);
    caps_pass<1><<<GRID, TPB, 0, stream>>>(x, W, v0, part);
    caps_reduce<1><<<32, 256, 0, stream>>>(part, v0, vsum, GRID);
    caps_pass<2><<<GRID, TPB, 0, stream>>>(x, W, vsum, part);
    caps_reduce<2><<<32, 256, 0, stream>>>(part, nullptr, out, GRID);
}

// Round 6
// 254.981 us; speedup vs baseline: 1.7031x; 1.7031x over previous
//
#include <hip/hip_runtime.h>
#include <math.h>

#define NIN 91392        // 17*21*16*16
#define DIN 8
#define DOUT 16
#define NCHUNK (NIN / 8) // 11424 chunks of 8 n
#define NSLICE 1428      // chunks per slice-pass: NCHUNK/NSLICE = 8 exactly
#define TPB 256
#define BPB 8            // batches per block (16 total, 2 halves)

// Pass kernel: recompute u_hat[j,n,o] = sum_i x[b,n,i]*W[j,n,i,o] on the fly.
// Layout: t = (g:3)(j:1)(o:4); block = (slice, batch-half).
// All 8 batches' x loaded into registers up front -> deep VMEM pipeline.
// PASS 0: s0 partial = sum_n u (c=0.5 folded into reduce)
// PASS>0: d via 32-lane butterfly, c = sigmoid(sgn*d), s partial
template<int PASS>
__global__ __launch_bounds__(TPB) void caps_pass(
    const float* __restrict__ x, const float* __restrict__ W,
    const float* __restrict__ vin, float* __restrict__ part)
{
    const int t = threadIdx.x;
    const int o = t & 15;          // output dim
    const int j = (t >> 4) & 1;    // capsule
    const int g = t >> 5;          // n-subgroup 0..7
    const int bid = blockIdx.x;
    const int slice = bid >> 1;    // 0..NSLICE-1
    const int bh = bid & 1;        // batch half

    const float sgn = j ? -1.f : 1.f;

    float vinreg[BPB];
    if (PASS > 0) {
        #pragma unroll
        for (int b = 0; b < BPB; ++b)
            vinreg[b] = sgn * vin[(bh * BPB + b) * 32 + (t & 31)];
    }

    float acc[BPB];
    #pragma unroll
    for (int b = 0; b < BPB; ++b) acc[b] = 0.f;

    for (int c = slice; c < NCHUNK; c += NSLICE) {
        const int n = c * 8 + g;

        // W[j][n][i][o]: 16 consecutive o-lanes read contiguous 64B per i
        float Wr[DIN];
        const float* wp = W + ((size_t)(j * NIN + n)) * (DIN * DOUT) + o;
        #pragma unroll
        for (int i = 0; i < DIN; ++i) Wr[i] = wp[i * DOUT];

        // all 8 batches' x up front: 16 independent float4 loads in flight
        float4 xa[BPB], xb[BPB];
        const float* xp = x + (size_t)n * DIN;
        #pragma unroll
        for (int b = 0; b < BPB; ++b) {
            const float* p = xp + (size_t)(bh * BPB + b) * (NIN * DIN);
            xa[b] = *(const float4*)(p);
            xb[b] = *(const float4*)(p + 4);
        }

        #pragma unroll
        for (int b = 0; b < BPB; ++b) {
            float u = xa[b].x*Wr[0] + xa[b].y*Wr[1] + xa[b].z*Wr[2] + xa[b].w*Wr[3]
                    + xb[b].x*Wr[4] + xb[b].y*Wr[5] + xb[b].z*Wr[6] + xb[b].w*Wr[7];
            if (PASS == 0) {
                acc[b] += u;
            } else {
                float m = vinreg[b] * u;           // sgn folded in
                m += __shfl_xor(m, 1);
                m += __shfl_xor(m, 2);
                m += __shfl_xor(m, 4);
                m += __shfl_xor(m, 8);
                m += __shfl_xor(m, 16);            // all 32 lanes hold d
                const float cc = __builtin_amdgcn_rcpf(1.f + __expf(-sgn * m));
                acc[b] += cc * u;
            }
        }
    }

    // fold the two 32-lane halves of each wave
    #pragma unroll
    for (int b = 0; b < BPB; ++b) acc[b] += __shfl_xor(acc[b], 32);

    // cross-wave reduce; stride 9 -> conflict-free banks (gcd(9,32)=1)
    __shared__ float red[4][32][9];
    const int wave = t >> 6;
    const int lane = t & 63;
    if (lane < 32) {
        #pragma unroll
        for (int b = 0; b < BPB; ++b) red[wave][lane][b] = acc[b];
    }
    __syncthreads();
    if (t < 32) {
        #pragma unroll
        for (int b = 0; b < BPB; ++b) {
            float s = red[0][t][b] + red[1][t][b] + red[2][t][b] + red[3][t][b];
            // column-major partials: part[col][slice], col = B*32 + (j*16+o)
            part[((size_t)(bh * BPB + b) * 32 + t) * NSLICE + slice] = s;
        }
    }
}

// Reduce partials -> s[b,j,o], squash -> v. 32 blocks = one per (b,j).
// Coalesced: column's NSLICE floats are contiguous.
// PASS 0: scale 0.5 (uniform softmax), write v0
// PASS 1: write v0+v1 (logits linear in accumulated v)
// PASS 2: write final v
template<int PASS>
__global__ __launch_bounds__(256) void caps_reduce(
    const float* __restrict__ part, const float* __restrict__ vprev,
    float* __restrict__ vout)
{
    const int blk = blockIdx.x;   // b*2 + j
    const int b = blk >> 1, j = blk & 1;
    const int t = threadIdx.x;
    const int o = t & 15;
    const int ch = t >> 4;
    const size_t base = ((size_t)b * 32 + j * 16 + o) * NSLICE;
    float s = 0.f;
    for (int g = ch; g < NSLICE; g += 16) s += part[base + g];
    __shared__ float red[256];
    red[t] = s;
    __syncthreads();
    if (t < 16) {
        float sv = 0.f;
        #pragma unroll
        for (int c = 0; c < 16; ++c) sv += red[c * 16 + t];
        if (PASS == 0) sv *= 0.5f;
        float sq = sv * sv;
        sq += __shfl_xor(sq, 1);
        sq += __shfl_xor(sq, 2);
        sq += __shfl_xor(sq, 4);
        sq += __shfl_xor(sq, 8);
        const float sn = sq;
        float v = sv * sn / ((1.f + sn) * sqrtf(sn + 1e-7f));
        if (PASS == 1) v += vprev[b * 32 + j * 16 + o];
        vout[b * 32 + j * 16 + o] = v;
    }
}

extern "C" void kernel_launch(void* const* d_in, const int* in_sizes, int n_in,
                              void* d_out, int out_size, void* d_ws, size_t ws_size,
                              hipStream_t stream) {
    const float* x = (const float*)d_in[0];
    const float* W = (const float*)d_in[1];
    float* out = (float*)d_out;

    float* part = (float*)d_ws;                       // 512*1428 floats = 2.9MB
    float* v0   = part + (size_t)512 * NSLICE;        // 512
    float* vsum = v0 + 512;                           // 512

    const int GRID = NSLICE * 2;                      // 2856 blocks

    caps_pass<0><<<GRID, TPB, 0, stream>>>(x, W, nullptr, part);
    caps_reduce<0><<<32, 256, 0, stream>>>(part, nullptr, v0);
    caps_pass<1><<<GRID, TPB, 0, stream>>>(x, W, v0, part);
    caps_reduce<1><<<32, 256, 0, stream>>>(part, v0, vsum);
    caps_pass<2><<<GRID, TPB, 0, stream>>>(x, W, vsum, part);
    caps_reduce<2><<<32, 256, 0, stream>>>(part, nullptr, out);
}